// Round 5
// baseline (183.185 us; speedup 1.0000x reference)
//
#include <hip/hip_runtime.h>
#include <hip/hip_fp16.h>

// RadialDescriptor: g[e,d] = sum_k c_table[ti,tj,d,k] * f[e,k]
//   f[e,k] = (T_k(x) + 1) * 0.5 * fc,  x = 2*(r/5-1)^2 - 1,
//   fc = 0.5*cos(pi*r/5)+0.5 for r<5 else 0.
//
// Round-3 post-mortem: kernel ~26us (absent from top-5; 180.6 total minus
// 2x73.6 fills + 7.5 restore), HBM floor ~21.5us (23.5MB fetch + 125MB
// write @ 6.9TB/s). Residual gap = LDS pipe: fp32 gather 256B/edge ->
// 4MB/CU / 85B/cyc ~= 19.6us, co-critical with HBM.
//
// f16 table in LDS -> 128B/edge, 8x ds_read_b128 (one b128 = one full
// descriptor's 8 coeffs). LDS time ~10-14us, strictly under the HBM write
// floor. Precision: |c|<=~4, f16 eps 2^-11 -> worst added error ~0.016 vs
// 0.116 headroom (f stays fp32). Row stride 144B (9 x 16B, odd) rotates
// spans across all 8 bank groups. Nontemporal stores (via native clang
// vector type -- HIP_vector_type rejected by the builtin) keep the 128MB
// output stream from churning L2.

#define KMAX 8
#define NDESC 8
#define HSTRIDE 72   // halves per table row: 144 B = 9*16 B

typedef float f32x4 __attribute__((ext_vector_type(4)));

struct alignas(16) Half8 { __half2 h[4]; };

__device__ __forceinline__ void edge_basis(float r, float* __restrict__ f) {
    float fc = (r < 5.0f) ? (0.5f * __cosf(0.62831853071795864769f * r) + 0.5f)
                          : 0.0f;
    float u = r * 0.2f - 1.0f;
    float x = 2.0f * u * u - 1.0f;
    float h = 0.5f * fc;
    f[0] = fc;                 // (T0+1)*h = 2h = fc
    f[1] = (x + 1.0f) * h;
    float t_prev = 1.0f, t_cur = x;
    #pragma unroll
    for (int k = 2; k < KMAX; ++k) {
        float t = 2.0f * x * t_cur - t_prev;
        t_prev = t_cur; t_cur = t;
        f[k] = (t + 1.0f) * h;
    }
}

__global__ __launch_bounds__(256, 4) void radial_kernel(
    const float* __restrict__ r_ij,
    const int*   __restrict__ type_i,
    const int*   __restrict__ type_j,
    const float* __restrict__ c_table,
    float*       __restrict__ out,
    int E)
{
    // lds row p: 64 halves (8 descriptors x 8 k) at halves offset p*HSTRIDE
    __shared__ __half lds_h[64 * HSTRIDE];
    const int tid = threadIdx.x;
    // 512 chunks of 8 floats -> 8 halves (16 B) each; chunk = p*8 + d
    for (int cidx = tid; cidx < 512; cidx += 256) {
        const float4 v0 = reinterpret_cast<const float4*>(c_table)[cidx * 2];
        const float4 v1 = reinterpret_cast<const float4*>(c_table)[cidx * 2 + 1];
        Half8 hv;
        hv.h[0] = __floats2half2_rn(v0.x, v0.y);
        hv.h[1] = __floats2half2_rn(v0.z, v0.w);
        hv.h[2] = __floats2half2_rn(v1.x, v1.y);
        hv.h[3] = __floats2half2_rn(v1.z, v1.w);
        int p = cidx >> 3, d = cidx & 7;
        *reinterpret_cast<Half8*>(&lds_h[p * HSTRIDE + d * 8]) = hv;
    }
    __syncthreads();

    const int stride = gridDim.x * blockDim.x;
    for (int e = blockIdx.x * blockDim.x + tid; e < E; e += stride) {
        float r = r_ij[e];
        int   p = (type_i[e] << 3) | type_j[e];

        float f[KMAX];
        edge_basis(r, f);

        const __half* rowbase = &lds_h[p * HSTRIDE];

        float acc[NDESC];
        #pragma unroll
        for (int d = 0; d < NDESC; ++d) {
            Half8 ch = *reinterpret_cast<const Half8*>(rowbase + d * 8);
            float2 c01 = __half22float2(ch.h[0]);
            float2 c23 = __half22float2(ch.h[1]);
            float2 c45 = __half22float2(ch.h[2]);
            float2 c67 = __half22float2(ch.h[3]);
            float a = c01.x * f[0];
            a = fmaf(c01.y, f[1], a);
            a = fmaf(c23.x, f[2], a);
            a = fmaf(c23.y, f[3], a);
            a = fmaf(c45.x, f[4], a);
            a = fmaf(c45.y, f[5], a);
            a = fmaf(c67.x, f[6], a);
            a = fmaf(c67.y, f[7], a);
            acc[d] = a;
        }

        f32x4* o = reinterpret_cast<f32x4*>(out + (size_t)e * 8);
        f32x4 v0 = { acc[0], acc[1], acc[2], acc[3] };
        f32x4 v1 = { acc[4], acc[5], acc[6], acc[7] };
        __builtin_nontemporal_store(v0, o);
        __builtin_nontemporal_store(v1, o + 1);
    }
}

extern "C" void kernel_launch(void* const* d_in, const int* in_sizes, int n_in,
                              void* d_out, int out_size, void* d_ws, size_t ws_size,
                              hipStream_t stream) {
    const float* r_ij   = (const float*)d_in[0];
    const int*   type_i = (const int*)d_in[1];
    const int*   type_j = (const int*)d_in[2];
    const float* c_tab  = (const float*)d_in[3];
    float* out = (float*)d_out;
    int E = in_sizes[0];

    dim3 block(256);
    dim3 grid(2048);
    radial_kernel<<<grid, block, 0, stream>>>(r_ij, type_i, type_j, c_tab, out, E);
}